// Round 14
// baseline (201.509 us; speedup 1.0000x reference)
//
#include <hip/hip_runtime.h>
#include <math.h>

// Problem constants
constexpr int NH    = 778;           // hand verts per batch
constexpr int GRIDC = 16;            // cells per axis (0.1 m cube -> 6.25 mm)
constexpr int NCELL = GRIDC * GRIDC * GRIDC;   // 4096
constexpr int CAP   = 40;            // bucket cap (Poisson mean ~9.8)
constexpr float CELL     = 0.1f / GRIDC;
constexpr float INV_CELL = GRIDC / 0.1f;

__device__ __forceinline__ int clampc(int v) {
    return min(GRIDC - 1, max(0, v));
}

// ws header (zeroed by the memset): accumulators + ticket + overflow count
struct Accs {
    double sum_d;    // +0
    double pen_sum;  // +8
    double att_sum;  // +16
    int pen_cnt;     // +24
    int att_cnt;     // +28
    int ticket;      // +32
    int ocnt;        // +36
};

// ---------------------------------------------------------------------------
// K1: bin obj points into per-(batch,cell) buckets. Overflow (idx >= CAP)
// goes to a global list tagged with batch (capacity = ALL points -> exact for
// any distribution). Insertion order is atomic-nondeterministic; min over the
// union is order-independent.
// ---------------------------------------------------------------------------
__global__ __launch_bounds__(256) void bin_kernel(
    const float* __restrict__ obj,   // [B, V, 3] flat
    int* __restrict__ cnt,           // [B*NCELL]
    int* __restrict__ ocnt,          // &Accs::ocnt
    float4* __restrict__ buckets,    // [B*NCELL*CAP]
    float4* __restrict__ ovf,        // [total] worst case
    int total, int V)
{
    const int i = blockIdx.x * 256 + threadIdx.x;
    if (i >= total) return;
    const float x = obj[3 * i + 0];
    const float y = obj[3 * i + 1];
    const float z = obj[3 * i + 2];
    const int cx = clampc((int)(x * INV_CELL));
    const int cy = clampc((int)(y * INV_CELL));
    const int cz = clampc((int)(z * INV_CELL));
    const int b = i / V;
    const int cell = b * NCELL + (cz * GRIDC + cy) * GRIDC + cx;
    const int idx = atomicAdd(&cnt[cell], 1);
    if (idx < CAP) {
        buckets[(size_t)cell * CAP + idx] = make_float4(x, y, z, 0.f);
    } else {
        const int oi = atomicAdd(ocnt, 1);   // oi < total always
        ovf[oi] = make_float4(x, y, z, __int_as_float(b));
    }
}

// ---------------------------------------------------------------------------
// K2: exact grid NN query (one wave per query, R12-proven) FUSED with the
// final loss reduction (R2-proven device-atomic + ticket pattern on regular
// launches — R13's cooperative launch failed silently; never again).
// Exactness: h lies inside its own cell; after completing cube radius r-1,
// any unscanned point is >= (r-1)*CELL away -> stop iff best <= ((r-1)*CELL)^2.
// ---------------------------------------------------------------------------
__global__ __launch_bounds__(256) void query_finalize_kernel(
    const float* __restrict__ hand,    // [B, NH, 3] flat
    const int* __restrict__ cnt,       // [B*NCELL]
    const float4* __restrict__ buckets,// [B*NCELL*CAP]
    const float4* __restrict__ ovf,
    Accs* __restrict__ acc,
    float* __restrict__ out,           // 6 outputs
    int B, int nblocks)
{
    const int wave = threadIdx.x >> 6;
    const int lane = threadIdx.x & 63;
    const int wid  = blockIdx.x * 4 + wave;   // one wave per query
    const int nw   = nblocks * 4;
    const int nq   = B * NH;
    const int on   = acc->ocnt;   // bin_kernel completed before this dispatch

    double l_sum = 0.0, l_pen = 0.0, l_att = 0.0;
    int l_pc = 0, l_ac = 0;

    for (int i = wid; i < nq; i += nw) {
        const int b = i / NH;
        const float hx = hand[3 * i + 0];
        const float hy = hand[3 * i + 1];
        const float hz = hand[3 * i + 2];
        const int hcx = clampc((int)(hx * INV_CELL));
        const int hcy = clampc((int)(hy * INV_CELL));
        const int hcz = clampc((int)(hz * INV_CELL));
        const int cbase = b * NCELL;
        float best = 3.4e38f;

        // radius-1 cube: 27 cells, 2 lanes per cell (lanes 0..53)
        if (lane < 54) {
            const int cl  = lane >> 1;
            const int sub = lane & 1;
            const int cx = hcx + (cl % 3) - 1;
            const int cy = hcy + ((cl / 3) % 3) - 1;
            const int cz = hcz + (cl / 9) - 1;
            if (cx >= 0 && cx < GRIDC && cy >= 0 && cy < GRIDC &&
                cz >= 0 && cz < GRIDC) {
                const int cell = cbase + (cz * GRIDC + cy) * GRIDC + cx;
                const int n = min(cnt[cell], CAP);
                const float4* bp = buckets + (size_t)cell * CAP;
                for (int k = sub; k < n; k += 2) {   // independent 16B loads
                    const float4 p = bp[k];
                    const float dx = p.x - hx, dy = p.y - hy, dz = p.z - hz;
                    best = fminf(best, fmaf(dx, dx, fmaf(dy, dy, dz * dz)));
                }
            }
        }
        // overflow list (normally empty), lane-strided
        for (int k = lane; k < on; k += 64) {
            const float4 p = ovf[k];
            if (__float_as_int(p.w) == b) {
                const float dx = p.x - hx, dy = p.y - hy, dz = p.z - hz;
                best = fminf(best, fmaf(dx, dx, fmaf(dy, dy, dz * dz)));
            }
        }
#pragma unroll
        for (int d = 1; d < 64; d <<= 1) best = fminf(best, __shfl_xor(best, d));

        // rare path: expanding shells until the bound certifies the min
        for (int r = 2; r < GRIDC; ++r) {
            const float bnd = (float)(r - 1) * CELL;
            if (best <= bnd * bnd) break;
            const int side = 2 * r + 1;
            const int ncl = side * side * side;
            for (int ci = lane; ci < ncl; ci += 64) {
                const int dx = ci % side - r;
                const int dy = (ci / side) % side - r;
                const int dz = ci / (side * side) - r;
                if (max(max(abs(dx), abs(dy)), abs(dz)) != r) continue;
                const int cx = hcx + dx, cy = hcy + dy, cz = hcz + dz;
                if (cx < 0 || cx >= GRIDC || cy < 0 || cy >= GRIDC ||
                    cz < 0 || cz >= GRIDC) continue;
                const int cell = cbase + (cz * GRIDC + cy) * GRIDC + cx;
                const int n = min(cnt[cell], CAP);
                const float4* bp = buckets + (size_t)cell * CAP;
                for (int k = 0; k < n; ++k) {
                    const float4 p = bp[k];
                    const float ax = p.x - hx, ay = p.y - hy, az = p.z - hz;
                    best = fminf(best, fmaf(ax, ax, fmaf(ay, ay, az * az)));
                }
            }
#pragma unroll
            for (int d = 1; d < 64; d <<= 1) best = fminf(best, __shfl_xor(best, d));
        }

        // loss contributions for query i (lane 0 only; no dist array)
        if (lane == 0) {
            const float d = sqrtf(fmaxf(best, 0.f));
            l_sum += (double)d;
            if (d < 0.005f) { const float t = 0.005f - d; l_pen += (double)(t * t); l_pc++; }
            const int n = i - b * NH;
            const bool isc = (n == 745) | (n == 317) | (n == 444) | (n == 556) |
                             (n == 673) | (n == 95)  | (n == 182) | (n == 234) |
                             (n == 279) | (n == 320);
            if (isc & (d > 0.005f) & (d < 0.01f)) { l_att += (double)(d * d); l_ac++; }
        }
    }

    // block reduce -> device atomics -> ticket -> last block writes outputs
    __shared__ double s_d[4], s_p[4], s_a[4];
    __shared__ int s_pc[4], s_ac[4], s_last;
    if (lane == 0) {
        s_d[wave] = l_sum; s_p[wave] = l_pen; s_a[wave] = l_att;
        s_pc[wave] = l_pc; s_ac[wave] = l_ac;
    }
    __syncthreads();
    if (threadIdx.x == 0) {
        const double bd = s_d[0] + s_d[1] + s_d[2] + s_d[3];
        const double bp = s_p[0] + s_p[1] + s_p[2] + s_p[3];
        const double ba = s_a[0] + s_a[1] + s_a[2] + s_a[3];
        const int bpc = s_pc[0] + s_pc[1] + s_pc[2] + s_pc[3];
        const int bac = s_ac[0] + s_ac[1] + s_ac[2] + s_ac[3];
        atomicAdd(&acc->sum_d, bd);
        atomicAdd(&acc->pen_sum, bp);
        atomicAdd(&acc->att_sum, ba);
        atomicAdd(&acc->pen_cnt, bpc);
        atomicAdd(&acc->att_cnt, bac);
        __threadfence();
        const int t = atomicAdd(&acc->ticket, 1);
        s_last = (t == nblocks - 1) ? 1 : 0;
    }
    __syncthreads();
    if (s_last && threadIdx.x == 0) {
        // coherent readbacks via atomics (cross-XCD safety, R2-proven)
        const double sum_d = atomicAdd(&acc->sum_d, 0.0);
        const double pen_s = atomicAdd(&acc->pen_sum, 0.0);
        const double att_s = atomicAdd(&acc->att_sum, 0.0);
        const int pc = atomicAdd(&acc->pen_cnt, 0);
        const int ac = atomicAdd(&acc->att_cnt, 0);
        const double pen_loss = pc > 0 ? pen_s / (double)pc : 0.0;
        const double att_loss = ac > 0 ? att_s / (double)ac : 0.0;
        out[0] = (float)(100.0 * pen_loss + 10.0 * att_loss);
        out[1] = (float)pen_loss;
        out[2] = (float)att_loss;
        out[3] = (float)(sum_d / (double)nq);
        out[4] = (float)ac;
        out[5] = (float)pc;
    }
}

// ---------------------------------------------------------------------------
// Fallback (ws too small for the grid): R10 brute kernel + finalize.
// ---------------------------------------------------------------------------
typedef float v2f __attribute__((ext_vector_type(2)));
constexpr int FT = 16, FG = 4, FBLK = 256, FCHUNK = 2560;
constexpr int FNBX = (NH + FG * FT - 1) / (FG * FT);
constexpr int FLPP = FCHUNK / FBLK, FPP = FLPP / 2;

__global__ __launch_bounds__(FBLK, 2) void nn_brute_kernel(
    const float* __restrict__ hand, const float* __restrict__ obj,
    unsigned int* __restrict__ minb, int V)
{
    __shared__ float s_red[4][16 * 65];
    const int bx = blockIdx.x, c = blockIdx.y, b = blockIdx.z;
    const int tid = threadIdx.x, wave = tid >> 6, lane = tid & 63;
    const int r = lane & 15, seg = lane >> 4;
    const float* ob = obj + (size_t)b * V * 3;
    const int base = c * FCHUNK + tid;
    v2f ox2[FPP], oy2[FPP], oz2[FPP], oq2[FPP];
#pragma unroll
    for (int p = 0; p < FPP; ++p) {
        const int ja = min(base + (2 * p + 0) * FBLK, V - 1);
        const int jb = min(base + (2 * p + 1) * FBLK, V - 1);
        const float xa = ob[3 * ja], ya = ob[3 * ja + 1], za = ob[3 * ja + 2];
        const float xb = ob[3 * jb], yb = ob[3 * jb + 1], zb = ob[3 * jb + 2];
        ox2[p] = (v2f){-2.f * xa, -2.f * xb};
        oy2[p] = (v2f){-2.f * ya, -2.f * yb};
        oz2[p] = (v2f){-2.f * za, -2.f * zb};
        oq2[p] = (v2f){fmaf(xa, xa, fmaf(ya, ya, za * za)),
                       fmaf(xb, xb, fmaf(yb, yb, zb * zb))};
    }
    const float* hb = hand + (size_t)b * NH * 3;
    float* sw = &s_red[wave][0];
#pragma unroll 1
    for (int g = 0; g < FG; ++g) {
        float hx[FT], hy[FT], hz[FT], m[FT];
#pragma unroll
        for (int t = 0; t < FT; ++t) {
            const int h = min((bx * FG + g) * FT + t, NH - 1);
            hx[t] = hb[3 * h]; hy[t] = hb[3 * h + 1]; hz[t] = hb[3 * h + 2];
            m[t] = 3.4e38f;
        }
#pragma unroll
        for (int p = 0; p < FPP; ++p) {
#pragma unroll
            for (int t = 0; t < FT; ++t) {
                v2f a = __builtin_elementwise_fma(ox2[p], (v2f){hx[t], hx[t]}, oq2[p]);
                a = __builtin_elementwise_fma(oy2[p], (v2f){hy[t], hy[t]}, a);
                a = __builtin_elementwise_fma(oz2[p], (v2f){hz[t], hz[t]}, a);
                m[t] = fminf(fminf(a.x, a.y), m[t]);
            }
        }
#pragma unroll
        for (int t = 0; t < FT; ++t) {
            const float hq = fmaf(hx[t], hx[t], fmaf(hy[t], hy[t], hz[t] * hz[t]));
            sw[t * 65 + lane] = m[t] + hq;
        }
        __builtin_amdgcn_wave_barrier();
        float v = 3.4e38f;
        const int rb = r * 65 + seg * 16;
#pragma unroll
        for (int j = 0; j < 16; ++j) v = fminf(v, sw[rb + j]);
        __builtin_amdgcn_wave_barrier();
        v = fminf(v, __shfl_xor(v, 16));
        v = fminf(v, __shfl_xor(v, 32));
        if (seg == 0) {
            const int hidx = (bx * FG + g) * FT + r;
            if (hidx < NH) {
                const unsigned bits = __float_as_uint(fmaxf(v, 0.f));
                unsigned int* p = &minb[b * NH + hidx];
                if (bits < *((volatile unsigned int*)p)) atomicMin(p, bits);
            }
        }
    }
}

__global__ __launch_bounds__(256) void finalize_kernel(
    const float* __restrict__ dist, float* __restrict__ out, int B)
{
    constexpr float COLL = 0.005f;
    constexpr float CONT = 0.01f;
    const int total = B * NH;
    const int tid = threadIdx.x;
    double sum_d = 0.0, pen_sum = 0.0, att_sum = 0.0;
    int pen_cnt = 0, att_cnt = 0;
    for (int i = tid; i < total; i += 256) {
        const float d = sqrtf(fmaxf(dist[i], 0.f));
        sum_d += (double)d;
        if (d < COLL) { const float t = COLL - d; pen_sum += (double)(t * t); pen_cnt++; }
        const int n = i % NH;
        const bool isc = (n == 745) | (n == 317) | (n == 444) | (n == 556) |
                         (n == 673) | (n == 95)  | (n == 182) | (n == 234) |
                         (n == 279) | (n == 320);
        if (isc & (d > COLL) & (d < CONT)) { att_sum += (double)(d * d); att_cnt++; }
    }
    __shared__ double sd[256], sp[256], sa[256];
    __shared__ int    cp[256], ca[256];
    sd[tid] = sum_d; sp[tid] = pen_sum; sa[tid] = att_sum;
    cp[tid] = pen_cnt; ca[tid] = att_cnt;
    __syncthreads();
    for (int off = 128; off > 0; off >>= 1) {
        if (tid < off) {
            sd[tid] += sd[tid + off]; sp[tid] += sp[tid + off];
            sa[tid] += sa[tid + off];
            cp[tid] += cp[tid + off]; ca[tid] += ca[tid + off];
        }
        __syncthreads();
    }
    if (tid == 0) {
        const double pen_loss = cp[0] > 0 ? sp[0] / (double)cp[0] : 0.0;
        const double att_loss = ca[0] > 0 ? sa[0] / (double)ca[0] : 0.0;
        out[0] = (float)(100.0 * pen_loss + 10.0 * att_loss);
        out[1] = (float)pen_loss;
        out[2] = (float)att_loss;
        out[3] = (float)(sd[0] / (double)total);
        out[4] = (float)ca[0];
        out[5] = (float)cp[0];
    }
}

extern "C" void kernel_launch(void* const* d_in, const int* in_sizes, int n_in,
                              void* d_out, int out_size, void* d_ws, size_t ws_size,
                              hipStream_t stream) {
    const float* hand = (const float*)d_in[0];  // [B, 778, 3] fp32
    const float* obj  = (const float*)d_in[1];  // [B, V, 3]   fp32
    // d_in[2]/d_in[3] (faces): unused by the loss

    const int B = in_sizes[0] / (NH * 3);
    const int V = in_sizes[1] / (B * 3);
    const int total = B * V;

    // ws layout: [header 256B: Accs][cnt B*NCELL][buckets][ovf]
    char* ws = (char*)d_ws;
    Accs* acc = (Accs*)ws;
    int* cnt = (int*)(ws + 256);
    const size_t cnt_bytes = (size_t)B * NCELL * sizeof(int);
    float4* buckets = (float4*)(ws + 256 + cnt_bytes);
    const size_t bkt_bytes = (size_t)B * NCELL * CAP * sizeof(float4);
    float4* ovf = (float4*)(ws + 256 + cnt_bytes + bkt_bytes);
    const size_t need = 256 + cnt_bytes + bkt_bytes + (size_t)total * sizeof(float4);

    if (ws_size >= need) {
        // zero header + cell counts (one node)
        hipMemsetAsync(ws, 0, 256 + cnt_bytes, stream);
        bin_kernel<<<(total + 255) / 256, 256, 0, stream>>>(
            obj, cnt, &acc->ocnt, buckets, ovf, total, V);
        const int nblocks = (B * NH + 3) / 4;   // one wave per query, 4/block
        query_finalize_kernel<<<nblocks, 256, 0, stream>>>(
            hand, cnt, buckets, ovf, acc, (float*)d_out, B, nblocks);
    } else {
        // brute-force fallback (uint bit-pattern mins == float d2)
        hipMemsetAsync(d_ws, 0x7F, (size_t)B * NH * sizeof(unsigned int), stream);
        dim3 grid(FNBX, (V + FCHUNK - 1) / FCHUNK, B);
        nn_brute_kernel<<<grid, FBLK, 0, stream>>>(hand, obj,
                                                   (unsigned int*)d_ws, V);
        finalize_kernel<<<1, 256, 0, stream>>>((const float*)d_ws,
                                               (float*)d_out, B);
    }
}

// Round 15
// 201.175 us; speedup vs baseline: 1.0017x; 1.0017x over previous
//
#include <hip/hip_runtime.h>
#include <math.h>

// Problem constants
constexpr int NH    = 778;           // hand verts per batch
constexpr int GRIDC = 16;            // cells per axis (0.1 m cube -> 6.25 mm)
constexpr int NCELL = GRIDC * GRIDC * GRIDC;   // 4096
constexpr int CAP   = 40;            // bucket cap (Poisson mean ~9.8)
constexpr float CELL     = 0.1f / GRIDC;
constexpr float INV_CELL = GRIDC / 0.1f;

__device__ __forceinline__ int clampc(int v) {
    return min(GRIDC - 1, max(0, v));
}

// ws header (zeroed by the memset): accumulators + ticket + overflow count
struct Accs {
    double sum_d;    // +0
    double pen_sum;  // +8
    double att_sum;  // +16
    int pen_cnt;     // +24
    int att_cnt;     // +28
    int ticket;      // +32
    int ocnt;        // +36
};

// ---------------------------------------------------------------------------
// K1: bin obj points into per-(batch,cell) buckets. Overflow (idx >= CAP)
// goes to a global list tagged with batch (capacity = ALL points -> exact for
// any distribution). Insertion order is atomic-nondeterministic; min over the
// union is order-independent.
// ---------------------------------------------------------------------------
__global__ __launch_bounds__(256) void bin_kernel(
    const float* __restrict__ obj,   // [B, V, 3] flat
    int* __restrict__ cnt,           // [B*NCELL]
    int* __restrict__ ocnt,          // &Accs::ocnt
    float4* __restrict__ buckets,    // [B*NCELL*CAP]
    float4* __restrict__ ovf,        // [total] worst case
    int total, int V)
{
    const int i = blockIdx.x * 256 + threadIdx.x;
    if (i >= total) return;
    const float x = obj[3 * i + 0];
    const float y = obj[3 * i + 1];
    const float z = obj[3 * i + 2];
    const int cx = clampc((int)(x * INV_CELL));
    const int cy = clampc((int)(y * INV_CELL));
    const int cz = clampc((int)(z * INV_CELL));
    const int b = i / V;
    const int cell = b * NCELL + (cz * GRIDC + cy) * GRIDC + cx;
    const int idx = atomicAdd(&cnt[cell], 1);
    if (idx < CAP) {
        buckets[(size_t)cell * CAP + idx] = make_float4(x, y, z, 0.f);
    } else {
        const int oi = atomicAdd(ocnt, 1);   // oi < total always
        ovf[oi] = make_float4(x, y, z, __int_as_float(b));
    }
}

// ---------------------------------------------------------------------------
// K2: exact grid NN query (one wave per query, R12-proven) fused with the
// final loss reduction. R14 post-mortem: __threadfence() per block = device-
// scope L2 writeback x1556 blocks = 133us of stall (warm replays: 2.6% VALU,
// 0.3MB traffic, 133us). Required ordering is only "this block's accumulator
// atomics complete before its ticket atomic" -> s_waitcnt vmcnt(0) (atomics
// are device-scope, executed at the coherence point; completion tracked by
// vmcnt). No L2 flush.
// Query exactness: h lies inside its own cell; after completing cube radius
// r-1, any unscanned point is >= (r-1)*CELL away -> stop iff
// best <= ((r-1)*CELL)^2.
// ---------------------------------------------------------------------------
__global__ __launch_bounds__(256) void query_finalize_kernel(
    const float* __restrict__ hand,    // [B, NH, 3] flat
    const int* __restrict__ cnt,       // [B*NCELL]
    const float4* __restrict__ buckets,// [B*NCELL*CAP]
    const float4* __restrict__ ovf,
    Accs* __restrict__ acc,
    float* __restrict__ out,           // 6 outputs
    int B, int nblocks)
{
    const int wave = threadIdx.x >> 6;
    const int lane = threadIdx.x & 63;
    const int wid  = blockIdx.x * 4 + wave;   // one wave per query
    const int nw   = nblocks * 4;
    const int nq   = B * NH;
    const int on   = acc->ocnt;   // bin_kernel completed before this dispatch

    double l_sum = 0.0, l_pen = 0.0, l_att = 0.0;
    int l_pc = 0, l_ac = 0;

    for (int i = wid; i < nq; i += nw) {
        const int b = i / NH;
        const float hx = hand[3 * i + 0];
        const float hy = hand[3 * i + 1];
        const float hz = hand[3 * i + 2];
        const int hcx = clampc((int)(hx * INV_CELL));
        const int hcy = clampc((int)(hy * INV_CELL));
        const int hcz = clampc((int)(hz * INV_CELL));
        const int cbase = b * NCELL;
        float best = 3.4e38f;

        // radius-1 cube: 27 cells, 2 lanes per cell (lanes 0..53)
        if (lane < 54) {
            const int cl  = lane >> 1;
            const int sub = lane & 1;
            const int cx = hcx + (cl % 3) - 1;
            const int cy = hcy + ((cl / 3) % 3) - 1;
            const int cz = hcz + (cl / 9) - 1;
            if (cx >= 0 && cx < GRIDC && cy >= 0 && cy < GRIDC &&
                cz >= 0 && cz < GRIDC) {
                const int cell = cbase + (cz * GRIDC + cy) * GRIDC + cx;
                const int n = min(cnt[cell], CAP);
                const float4* bp = buckets + (size_t)cell * CAP;
                for (int k = sub; k < n; k += 2) {   // independent 16B loads
                    const float4 p = bp[k];
                    const float dx = p.x - hx, dy = p.y - hy, dz = p.z - hz;
                    best = fminf(best, fmaf(dx, dx, fmaf(dy, dy, dz * dz)));
                }
            }
        }
        // overflow list (normally empty), lane-strided
        for (int k = lane; k < on; k += 64) {
            const float4 p = ovf[k];
            if (__float_as_int(p.w) == b) {
                const float dx = p.x - hx, dy = p.y - hy, dz = p.z - hz;
                best = fminf(best, fmaf(dx, dx, fmaf(dy, dy, dz * dz)));
            }
        }
#pragma unroll
        for (int d = 1; d < 64; d <<= 1) best = fminf(best, __shfl_xor(best, d));

        // rare path: expanding shells until the bound certifies the min
        for (int r = 2; r < GRIDC; ++r) {
            const float bnd = (float)(r - 1) * CELL;
            if (best <= bnd * bnd) break;
            const int side = 2 * r + 1;
            const int ncl = side * side * side;
            for (int ci = lane; ci < ncl; ci += 64) {
                const int dx = ci % side - r;
                const int dy = (ci / side) % side - r;
                const int dz = ci / (side * side) - r;
                if (max(max(abs(dx), abs(dy)), abs(dz)) != r) continue;
                const int cx = hcx + dx, cy = hcy + dy, cz = hcz + dz;
                if (cx < 0 || cx >= GRIDC || cy < 0 || cy >= GRIDC ||
                    cz < 0 || cz >= GRIDC) continue;
                const int cell = cbase + (cz * GRIDC + cy) * GRIDC + cx;
                const int n = min(cnt[cell], CAP);
                const float4* bp = buckets + (size_t)cell * CAP;
                for (int k = 0; k < n; ++k) {
                    const float4 p = bp[k];
                    const float ax = p.x - hx, ay = p.y - hy, az = p.z - hz;
                    best = fminf(best, fmaf(ax, ax, fmaf(ay, ay, az * az)));
                }
            }
#pragma unroll
            for (int d = 1; d < 64; d <<= 1) best = fminf(best, __shfl_xor(best, d));
        }

        // loss contributions for query i (lane 0 only; no dist array)
        if (lane == 0) {
            const float d = sqrtf(fmaxf(best, 0.f));
            l_sum += (double)d;
            if (d < 0.005f) { const float t = 0.005f - d; l_pen += (double)(t * t); l_pc++; }
            const int n = i - b * NH;
            const bool isc = (n == 745) | (n == 317) | (n == 444) | (n == 556) |
                             (n == 673) | (n == 95)  | (n == 182) | (n == 234) |
                             (n == 279) | (n == 320);
            if (isc & (d > 0.005f) & (d < 0.01f)) { l_att += (double)(d * d); l_ac++; }
        }
    }

    // block reduce -> device atomics -> vmcnt drain -> ticket -> last block
    __shared__ double s_d[4], s_p[4], s_a[4];
    __shared__ int s_pc[4], s_ac[4], s_last;
    if (lane == 0) {
        s_d[wave] = l_sum; s_p[wave] = l_pen; s_a[wave] = l_att;
        s_pc[wave] = l_pc; s_ac[wave] = l_ac;
    }
    __syncthreads();
    if (threadIdx.x == 0) {
        const double bd = s_d[0] + s_d[1] + s_d[2] + s_d[3];
        const double bp = s_p[0] + s_p[1] + s_p[2] + s_p[3];
        const double ba = s_a[0] + s_a[1] + s_a[2] + s_a[3];
        const int bpc = s_pc[0] + s_pc[1] + s_pc[2] + s_pc[3];
        const int bac = s_ac[0] + s_ac[1] + s_ac[2] + s_ac[3];
        atomicAdd(&acc->sum_d, bd);
        atomicAdd(&acc->pen_sum, bp);
        atomicAdd(&acc->att_sum, ba);
        atomicAdd(&acc->pen_cnt, bpc);
        atomicAdd(&acc->att_cnt, bac);
        // wait for the accumulator atomics to COMPLETE at the coherence point
        // (device-scope atomics; completion tracked by vmcnt). NOT
        // __threadfence(): that forces a per-block L2 writeback (R14: 133us).
        asm volatile("s_waitcnt vmcnt(0)" ::: "memory");
        const int t = atomicAdd(&acc->ticket, 1);
        s_last = (t == nblocks - 1) ? 1 : 0;
    }
    __syncthreads();
    if (s_last && threadIdx.x == 0) {
        // coherent readbacks via atomics (cross-XCD safety, R2-proven)
        const double sum_d = atomicAdd(&acc->sum_d, 0.0);
        const double pen_s = atomicAdd(&acc->pen_sum, 0.0);
        const double att_s = atomicAdd(&acc->att_sum, 0.0);
        const int pc = atomicAdd(&acc->pen_cnt, 0);
        const int ac = atomicAdd(&acc->att_cnt, 0);
        const double pen_loss = pc > 0 ? pen_s / (double)pc : 0.0;
        const double att_loss = ac > 0 ? att_s / (double)ac : 0.0;
        out[0] = (float)(100.0 * pen_loss + 10.0 * att_loss);
        out[1] = (float)pen_loss;
        out[2] = (float)att_loss;
        out[3] = (float)(sum_d / (double)nq);
        out[4] = (float)ac;
        out[5] = (float)pc;
    }
}

// ---------------------------------------------------------------------------
// Fallback (ws too small for the grid): R10 brute kernel + finalize.
// ---------------------------------------------------------------------------
typedef float v2f __attribute__((ext_vector_type(2)));
constexpr int FT = 16, FG = 4, FBLK = 256, FCHUNK = 2560;
constexpr int FNBX = (NH + FG * FT - 1) / (FG * FT);
constexpr int FLPP = FCHUNK / FBLK, FPP = FLPP / 2;

__global__ __launch_bounds__(FBLK, 2) void nn_brute_kernel(
    const float* __restrict__ hand, const float* __restrict__ obj,
    unsigned int* __restrict__ minb, int V)
{
    __shared__ float s_red[4][16 * 65];
    const int bx = blockIdx.x, c = blockIdx.y, b = blockIdx.z;
    const int tid = threadIdx.x, wave = tid >> 6, lane = tid & 63;
    const int r = lane & 15, seg = lane >> 4;
    const float* ob = obj + (size_t)b * V * 3;
    const int base = c * FCHUNK + tid;
    v2f ox2[FPP], oy2[FPP], oz2[FPP], oq2[FPP];
#pragma unroll
    for (int p = 0; p < FPP; ++p) {
        const int ja = min(base + (2 * p + 0) * FBLK, V - 1);
        const int jb = min(base + (2 * p + 1) * FBLK, V - 1);
        const float xa = ob[3 * ja], ya = ob[3 * ja + 1], za = ob[3 * ja + 2];
        const float xb = ob[3 * jb], yb = ob[3 * jb + 1], zb = ob[3 * jb + 2];
        ox2[p] = (v2f){-2.f * xa, -2.f * xb};
        oy2[p] = (v2f){-2.f * ya, -2.f * yb};
        oz2[p] = (v2f){-2.f * za, -2.f * zb};
        oq2[p] = (v2f){fmaf(xa, xa, fmaf(ya, ya, za * za)),
                       fmaf(xb, xb, fmaf(yb, yb, zb * zb))};
    }
    const float* hb = hand + (size_t)b * NH * 3;
    float* sw = &s_red[wave][0];
#pragma unroll 1
    for (int g = 0; g < FG; ++g) {
        float hx[FT], hy[FT], hz[FT], m[FT];
#pragma unroll
        for (int t = 0; t < FT; ++t) {
            const int h = min((bx * FG + g) * FT + t, NH - 1);
            hx[t] = hb[3 * h]; hy[t] = hb[3 * h + 1]; hz[t] = hb[3 * h + 2];
            m[t] = 3.4e38f;
        }
#pragma unroll
        for (int p = 0; p < FPP; ++p) {
#pragma unroll
            for (int t = 0; t < FT; ++t) {
                v2f a = __builtin_elementwise_fma(ox2[p], (v2f){hx[t], hx[t]}, oq2[p]);
                a = __builtin_elementwise_fma(oy2[p], (v2f){hy[t], hy[t]}, a);
                a = __builtin_elementwise_fma(oz2[p], (v2f){hz[t], hz[t]}, a);
                m[t] = fminf(fminf(a.x, a.y), m[t]);
            }
        }
#pragma unroll
        for (int t = 0; t < FT; ++t) {
            const float hq = fmaf(hx[t], hx[t], fmaf(hy[t], hy[t], hz[t] * hz[t]));
            sw[t * 65 + lane] = m[t] + hq;
        }
        __builtin_amdgcn_wave_barrier();
        float v = 3.4e38f;
        const int rb = r * 65 + seg * 16;
#pragma unroll
        for (int j = 0; j < 16; ++j) v = fminf(v, sw[rb + j]);
        __builtin_amdgcn_wave_barrier();
        v = fminf(v, __shfl_xor(v, 16));
        v = fminf(v, __shfl_xor(v, 32));
        if (seg == 0) {
            const int hidx = (bx * FG + g) * FT + r;
            if (hidx < NH) {
                const unsigned bits = __float_as_uint(fmaxf(v, 0.f));
                unsigned int* p = &minb[b * NH + hidx];
                if (bits < *((volatile unsigned int*)p)) atomicMin(p, bits);
            }
        }
    }
}

__global__ __launch_bounds__(256) void finalize_kernel(
    const float* __restrict__ dist, float* __restrict__ out, int B)
{
    constexpr float COLL = 0.005f;
    constexpr float CONT = 0.01f;
    const int total = B * NH;
    const int tid = threadIdx.x;
    double sum_d = 0.0, pen_sum = 0.0, att_sum = 0.0;
    int pen_cnt = 0, att_cnt = 0;
    for (int i = tid; i < total; i += 256) {
        const float d = sqrtf(fmaxf(dist[i], 0.f));
        sum_d += (double)d;
        if (d < COLL) { const float t = COLL - d; pen_sum += (double)(t * t); pen_cnt++; }
        const int n = i % NH;
        const bool isc = (n == 745) | (n == 317) | (n == 444) | (n == 556) |
                         (n == 673) | (n == 95)  | (n == 182) | (n == 234) |
                         (n == 279) | (n == 320);
        if (isc & (d > COLL) & (d < CONT)) { att_sum += (double)(d * d); att_cnt++; }
    }
    __shared__ double sd[256], sp[256], sa[256];
    __shared__ int    cp[256], ca[256];
    sd[tid] = sum_d; sp[tid] = pen_sum; sa[tid] = att_sum;
    cp[tid] = pen_cnt; ca[tid] = att_cnt;
    __syncthreads();
    for (int off = 128; off > 0; off >>= 1) {
        if (tid < off) {
            sd[tid] += sd[tid + off]; sp[tid] += sp[tid + off];
            sa[tid] += sa[tid + off];
            cp[tid] += cp[tid + off]; ca[tid] += ca[tid + off];
        }
        __syncthreads();
    }
    if (tid == 0) {
        const double pen_loss = cp[0] > 0 ? sp[0] / (double)cp[0] : 0.0;
        const double att_loss = ca[0] > 0 ? sa[0] / (double)ca[0] : 0.0;
        out[0] = (float)(100.0 * pen_loss + 10.0 * att_loss);
        out[1] = (float)pen_loss;
        out[2] = (float)att_loss;
        out[3] = (float)(sd[0] / (double)total);
        out[4] = (float)ca[0];
        out[5] = (float)cp[0];
    }
}

extern "C" void kernel_launch(void* const* d_in, const int* in_sizes, int n_in,
                              void* d_out, int out_size, void* d_ws, size_t ws_size,
                              hipStream_t stream) {
    const float* hand = (const float*)d_in[0];  // [B, 778, 3] fp32
    const float* obj  = (const float*)d_in[1];  // [B, V, 3]   fp32
    // d_in[2]/d_in[3] (faces): unused by the loss

    const int B = in_sizes[0] / (NH * 3);
    const int V = in_sizes[1] / (B * 3);
    const int total = B * V;

    // ws layout: [header 256B: Accs][cnt B*NCELL][buckets][ovf]
    char* ws = (char*)d_ws;
    Accs* acc = (Accs*)ws;
    int* cnt = (int*)(ws + 256);
    const size_t cnt_bytes = (size_t)B * NCELL * sizeof(int);
    float4* buckets = (float4*)(ws + 256 + cnt_bytes);
    const size_t bkt_bytes = (size_t)B * NCELL * CAP * sizeof(float4);
    float4* ovf = (float4*)(ws + 256 + cnt_bytes + bkt_bytes);
    const size_t need = 256 + cnt_bytes + bkt_bytes + (size_t)total * sizeof(float4);

    if (ws_size >= need) {
        // zero header + cell counts (one node)
        hipMemsetAsync(ws, 0, 256 + cnt_bytes, stream);
        bin_kernel<<<(total + 255) / 256, 256, 0, stream>>>(
            obj, cnt, &acc->ocnt, buckets, ovf, total, V);
        const int nblocks = (B * NH + 3) / 4;   // one wave per query, 4/block
        query_finalize_kernel<<<nblocks, 256, 0, stream>>>(
            hand, cnt, buckets, ovf, acc, (float*)d_out, B, nblocks);
    } else {
        // brute-force fallback (uint bit-pattern mins == float d2)
        hipMemsetAsync(d_ws, 0x7F, (size_t)B * NH * sizeof(unsigned int), stream);
        dim3 grid(FNBX, (V + FCHUNK - 1) / FCHUNK, B);
        nn_brute_kernel<<<grid, FBLK, 0, stream>>>(hand, obj,
                                                   (unsigned int*)d_ws, V);
        finalize_kernel<<<1, 256, 0, stream>>>((const float*)d_ws,
                                               (float*)d_out, B);
    }
}

// Round 16
// 101.816 us; speedup vs baseline: 1.9792x; 1.9759x over previous
//
#include <hip/hip_runtime.h>
#include <math.h>

// Problem constants
constexpr int NH    = 778;           // hand verts per batch
constexpr int GRIDC = 16;            // cells per axis (0.1 m cube -> 6.25 mm)
constexpr int NCELL = GRIDC * GRIDC * GRIDC;   // 4096
constexpr int CAP   = 40;            // bucket cap (Poisson mean ~9.8)
constexpr float CELL     = 0.1f / GRIDC;
constexpr float INV_CELL = GRIDC / 0.1f;

__device__ __forceinline__ int clampc(int v) {
    return min(GRIDC - 1, max(0, v));
}

// ws header (zeroed by the memset): ticket + overflow count
struct Accs {
    int ticket;   // +0
    int ocnt;     // +4
};

// per-block partial sums: one 64B line per block -> agent-scope atomic STORES
// to distinct lines pipeline fully (no RMW, no same-address serialization).
struct alignas(64) Part {
    double sum_d;               // +0
    double pen_sum;             // +8
    double att_sum;             // +16
    unsigned long long cnts;    // +24: (att_cnt<<32)|pen_cnt
};

// ---------------------------------------------------------------------------
// K1: bin obj points into per-(batch,cell) buckets (R11-proven exact).
// Overflow (idx >= CAP) -> global list tagged with batch.
// ---------------------------------------------------------------------------
__global__ __launch_bounds__(256) void bin_kernel(
    const float* __restrict__ obj,   // [B, V, 3] flat
    int* __restrict__ cnt,           // [B*NCELL]
    int* __restrict__ ocnt,          // &Accs::ocnt
    float4* __restrict__ buckets,    // [B*NCELL*CAP]
    float4* __restrict__ ovf,        // [total] worst case
    int total, int V)
{
    const int i = blockIdx.x * 256 + threadIdx.x;
    if (i >= total) return;
    const float x = obj[3 * i + 0];
    const float y = obj[3 * i + 1];
    const float z = obj[3 * i + 2];
    const int cx = clampc((int)(x * INV_CELL));
    const int cy = clampc((int)(y * INV_CELL));
    const int cz = clampc((int)(z * INV_CELL));
    const int b = i / V;
    const int cell = b * NCELL + (cz * GRIDC + cy) * GRIDC + cx;
    const int idx = atomicAdd(&cnt[cell], 1);
    if (idx < CAP) {
        buckets[(size_t)cell * CAP + idx] = make_float4(x, y, z, 0.f);
    } else {
        const int oi = atomicAdd(ocnt, 1);   // oi < total always
        ovf[oi] = make_float4(x, y, z, __int_as_float(b));
    }
}

// ---------------------------------------------------------------------------
// K2: exact grid NN query (one wave per query slot, 4 queries/wave) fused
// with the final reduction.
// R14/R15 post-mortem: 1556 blocks x 6 same-line RMW atomics = 9336 x ~13ns
// serialized at the coherence point = the 120us stall. R16: per-block partials
// via agent-scope relaxed atomic STORES to DISTINCT 64B slots (pipelined,
// no RMW), vmcnt(0) drain, then exactly ONE ticket RMW per block with only
// 389 blocks. Last block reads slots in parallel (agent-scope atomic loads,
// coherent because every predecessor's stores completed before its ticket).
// Query exactness: h lies inside its own cell; after completing cube radius
// r-1, any unscanned point is >= (r-1)*CELL away -> stop iff
// best <= ((r-1)*CELL)^2.
// ---------------------------------------------------------------------------
__global__ __launch_bounds__(256) void query_finalize_kernel(
    const float* __restrict__ hand,    // [B, NH, 3] flat
    const int* __restrict__ cnt,       // [B*NCELL]
    const float4* __restrict__ buckets,// [B*NCELL*CAP]
    const float4* __restrict__ ovf,
    Accs* __restrict__ acc,
    Part* __restrict__ parts,          // [nblocks]
    float* __restrict__ out,           // 6 outputs
    int B, int nblocks)
{
    const int wave = threadIdx.x >> 6;
    const int lane = threadIdx.x & 63;
    const int wid  = blockIdx.x * 4 + wave;
    const int nw   = nblocks * 4;
    const int nq   = B * NH;
    const int on   = acc->ocnt;   // bin_kernel completed before this dispatch

    double l_sum = 0.0, l_pen = 0.0, l_att = 0.0;
    int l_pc = 0, l_ac = 0;

    for (int i = wid; i < nq; i += nw) {
        const int b = i / NH;
        const float hx = hand[3 * i + 0];
        const float hy = hand[3 * i + 1];
        const float hz = hand[3 * i + 2];
        const int hcx = clampc((int)(hx * INV_CELL));
        const int hcy = clampc((int)(hy * INV_CELL));
        const int hcz = clampc((int)(hz * INV_CELL));
        const int cbase = b * NCELL;
        float best = 3.4e38f;

        // radius-1 cube: 27 cells, 2 lanes per cell (lanes 0..53)
        if (lane < 54) {
            const int cl  = lane >> 1;
            const int sub = lane & 1;
            const int cx = hcx + (cl % 3) - 1;
            const int cy = hcy + ((cl / 3) % 3) - 1;
            const int cz = hcz + (cl / 9) - 1;
            if (cx >= 0 && cx < GRIDC && cy >= 0 && cy < GRIDC &&
                cz >= 0 && cz < GRIDC) {
                const int cell = cbase + (cz * GRIDC + cy) * GRIDC + cx;
                const int n = min(cnt[cell], CAP);
                const float4* bp = buckets + (size_t)cell * CAP;
                for (int k = sub; k < n; k += 2) {   // independent 16B loads
                    const float4 p = bp[k];
                    const float dx = p.x - hx, dy = p.y - hy, dz = p.z - hz;
                    best = fminf(best, fmaf(dx, dx, fmaf(dy, dy, dz * dz)));
                }
            }
        }
        // overflow list (normally empty), lane-strided
        for (int k = lane; k < on; k += 64) {
            const float4 p = ovf[k];
            if (__float_as_int(p.w) == b) {
                const float dx = p.x - hx, dy = p.y - hy, dz = p.z - hz;
                best = fminf(best, fmaf(dx, dx, fmaf(dy, dy, dz * dz)));
            }
        }
#pragma unroll
        for (int d = 1; d < 64; d <<= 1) best = fminf(best, __shfl_xor(best, d));

        // rare path: expanding shells until the bound certifies the min
        for (int r = 2; r < GRIDC; ++r) {
            const float bnd = (float)(r - 1) * CELL;
            if (best <= bnd * bnd) break;
            const int side = 2 * r + 1;
            const int ncl = side * side * side;
            for (int ci = lane; ci < ncl; ci += 64) {
                const int dx = ci % side - r;
                const int dy = (ci / side) % side - r;
                const int dz = ci / (side * side) - r;
                if (max(max(abs(dx), abs(dy)), abs(dz)) != r) continue;
                const int cx = hcx + dx, cy = hcy + dy, cz = hcz + dz;
                if (cx < 0 || cx >= GRIDC || cy < 0 || cy >= GRIDC ||
                    cz < 0 || cz >= GRIDC) continue;
                const int cell = cbase + (cz * GRIDC + cy) * GRIDC + cx;
                const int n = min(cnt[cell], CAP);
                const float4* bp = buckets + (size_t)cell * CAP;
                for (int k = 0; k < n; ++k) {
                    const float4 p = bp[k];
                    const float ax = p.x - hx, ay = p.y - hy, az = p.z - hz;
                    best = fminf(best, fmaf(ax, ax, fmaf(ay, ay, az * az)));
                }
            }
#pragma unroll
            for (int d = 1; d < 64; d <<= 1) best = fminf(best, __shfl_xor(best, d));
        }

        // loss contributions for query i (lane 0 only)
        if (lane == 0) {
            const float d = sqrtf(fmaxf(best, 0.f));
            l_sum += (double)d;
            if (d < 0.005f) { const float t = 0.005f - d; l_pen += (double)(t * t); l_pc++; }
            const int n = i - b * NH;
            const bool isc = (n == 745) | (n == 317) | (n == 444) | (n == 556) |
                             (n == 673) | (n == 95)  | (n == 182) | (n == 234) |
                             (n == 279) | (n == 320);
            if (isc & (d > 0.005f) & (d < 0.01f)) { l_att += (double)(d * d); l_ac++; }
        }
    }

    // block reduce (LDS) -> agent-scope STORES to this block's slot ->
    // vmcnt drain -> ONE ticket RMW -> last block reduces the slots.
    __shared__ double s_d[4], s_p[4], s_a[4];
    __shared__ int s_pc[4], s_ac[4], s_last;
    if (lane == 0) {
        s_d[wave] = l_sum; s_p[wave] = l_pen; s_a[wave] = l_att;
        s_pc[wave] = l_pc; s_ac[wave] = l_ac;
    }
    __syncthreads();
    if (threadIdx.x == 0) {
        Part* slot = &parts[blockIdx.x];
        const double bd = s_d[0] + s_d[1] + s_d[2] + s_d[3];
        const double bp = s_p[0] + s_p[1] + s_p[2] + s_p[3];
        const double ba = s_a[0] + s_a[1] + s_a[2] + s_a[3];
        const unsigned long long bc =
            ((unsigned long long)(unsigned)(s_ac[0] + s_ac[1] + s_ac[2] + s_ac[3]) << 32) |
            (unsigned)(s_pc[0] + s_pc[1] + s_pc[2] + s_pc[3]);
        __hip_atomic_store(&slot->sum_d,   bd, __ATOMIC_RELAXED, __HIP_MEMORY_SCOPE_AGENT);
        __hip_atomic_store(&slot->pen_sum, bp, __ATOMIC_RELAXED, __HIP_MEMORY_SCOPE_AGENT);
        __hip_atomic_store(&slot->att_sum, ba, __ATOMIC_RELAXED, __HIP_MEMORY_SCOPE_AGENT);
        __hip_atomic_store(&slot->cnts,    bc, __ATOMIC_RELAXED, __HIP_MEMORY_SCOPE_AGENT);
        // wait for the slot stores to COMPLETE at the coherence point, then
        // the single ticket RMW (the only same-line atomic in the kernel).
        asm volatile("s_waitcnt vmcnt(0)" ::: "memory");
        const int t = atomicAdd(&acc->ticket, 1);
        s_last = (t == nblocks - 1) ? 1 : 0;
    }
    __syncthreads();
    if (!s_last) return;

    // last block: parallel slot readback (agent-scope loads) + LDS reduce
    double f_d = 0.0, f_p = 0.0, f_a = 0.0;
    int f_pc = 0, f_ac = 0;
    for (int s = threadIdx.x; s < nblocks; s += 256) {
        f_d += __hip_atomic_load(&parts[s].sum_d,   __ATOMIC_RELAXED, __HIP_MEMORY_SCOPE_AGENT);
        f_p += __hip_atomic_load(&parts[s].pen_sum, __ATOMIC_RELAXED, __HIP_MEMORY_SCOPE_AGENT);
        f_a += __hip_atomic_load(&parts[s].att_sum, __ATOMIC_RELAXED, __HIP_MEMORY_SCOPE_AGENT);
        const unsigned long long c =
            __hip_atomic_load(&parts[s].cnts, __ATOMIC_RELAXED, __HIP_MEMORY_SCOPE_AGENT);
        f_pc += (int)(unsigned)(c & 0xFFFFFFFFull);
        f_ac += (int)(unsigned)(c >> 32);
    }
    __shared__ double r_d[256], r_p[256], r_a[256];
    __shared__ int r_pc[256], r_ac[256];
    r_d[threadIdx.x] = f_d; r_p[threadIdx.x] = f_p; r_a[threadIdx.x] = f_a;
    r_pc[threadIdx.x] = f_pc; r_ac[threadIdx.x] = f_ac;
    __syncthreads();
    for (int off = 128; off > 0; off >>= 1) {
        if (threadIdx.x < off) {
            r_d[threadIdx.x] += r_d[threadIdx.x + off];
            r_p[threadIdx.x] += r_p[threadIdx.x + off];
            r_a[threadIdx.x] += r_a[threadIdx.x + off];
            r_pc[threadIdx.x] += r_pc[threadIdx.x + off];
            r_ac[threadIdx.x] += r_ac[threadIdx.x + off];
        }
        __syncthreads();
    }
    if (threadIdx.x == 0) {
        const int pc = r_pc[0], ac = r_ac[0];
        const double pen_loss = pc > 0 ? r_p[0] / (double)pc : 0.0;
        const double att_loss = ac > 0 ? r_a[0] / (double)ac : 0.0;
        out[0] = (float)(100.0 * pen_loss + 10.0 * att_loss);
        out[1] = (float)pen_loss;
        out[2] = (float)att_loss;
        out[3] = (float)(r_d[0] / (double)nq);
        out[4] = (float)ac;
        out[5] = (float)pc;
    }
}

// ---------------------------------------------------------------------------
// Fallback (ws too small for the grid): R10 brute kernel + finalize.
// ---------------------------------------------------------------------------
typedef float v2f __attribute__((ext_vector_type(2)));
constexpr int FT = 16, FG = 4, FBLK = 256, FCHUNK = 2560;
constexpr int FNBX = (NH + FG * FT - 1) / (FG * FT);
constexpr int FLPP = FCHUNK / FBLK, FPP = FLPP / 2;

__global__ __launch_bounds__(FBLK, 2) void nn_brute_kernel(
    const float* __restrict__ hand, const float* __restrict__ obj,
    unsigned int* __restrict__ minb, int V)
{
    __shared__ float s_red[4][16 * 65];
    const int bx = blockIdx.x, c = blockIdx.y, b = blockIdx.z;
    const int tid = threadIdx.x, wave = tid >> 6, lane = tid & 63;
    const int r = lane & 15, seg = lane >> 4;
    const float* ob = obj + (size_t)b * V * 3;
    const int base = c * FCHUNK + tid;
    v2f ox2[FPP], oy2[FPP], oz2[FPP], oq2[FPP];
#pragma unroll
    for (int p = 0; p < FPP; ++p) {
        const int ja = min(base + (2 * p + 0) * FBLK, V - 1);
        const int jb = min(base + (2 * p + 1) * FBLK, V - 1);
        const float xa = ob[3 * ja], ya = ob[3 * ja + 1], za = ob[3 * ja + 2];
        const float xb = ob[3 * jb], yb = ob[3 * jb + 1], zb = ob[3 * jb + 2];
        ox2[p] = (v2f){-2.f * xa, -2.f * xb};
        oy2[p] = (v2f){-2.f * ya, -2.f * yb};
        oz2[p] = (v2f){-2.f * za, -2.f * zb};
        oq2[p] = (v2f){fmaf(xa, xa, fmaf(ya, ya, za * za)),
                       fmaf(xb, xb, fmaf(yb, yb, zb * zb))};
    }
    const float* hb = hand + (size_t)b * NH * 3;
    float* sw = &s_red[wave][0];
#pragma unroll 1
    for (int g = 0; g < FG; ++g) {
        float hx[FT], hy[FT], hz[FT], m[FT];
#pragma unroll
        for (int t = 0; t < FT; ++t) {
            const int h = min((bx * FG + g) * FT + t, NH - 1);
            hx[t] = hb[3 * h]; hy[t] = hb[3 * h + 1]; hz[t] = hb[3 * h + 2];
            m[t] = 3.4e38f;
        }
#pragma unroll
        for (int p = 0; p < FPP; ++p) {
#pragma unroll
            for (int t = 0; t < FT; ++t) {
                v2f a = __builtin_elementwise_fma(ox2[p], (v2f){hx[t], hx[t]}, oq2[p]);
                a = __builtin_elementwise_fma(oy2[p], (v2f){hy[t], hy[t]}, a);
                a = __builtin_elementwise_fma(oz2[p], (v2f){hz[t], hz[t]}, a);
                m[t] = fminf(fminf(a.x, a.y), m[t]);
            }
        }
#pragma unroll
        for (int t = 0; t < FT; ++t) {
            const float hq = fmaf(hx[t], hx[t], fmaf(hy[t], hy[t], hz[t] * hz[t]));
            sw[t * 65 + lane] = m[t] + hq;
        }
        __builtin_amdgcn_wave_barrier();
        float v = 3.4e38f;
        const int rb = r * 65 + seg * 16;
#pragma unroll
        for (int j = 0; j < 16; ++j) v = fminf(v, sw[rb + j]);
        __builtin_amdgcn_wave_barrier();
        v = fminf(v, __shfl_xor(v, 16));
        v = fminf(v, __shfl_xor(v, 32));
        if (seg == 0) {
            const int hidx = (bx * FG + g) * FT + r;
            if (hidx < NH) {
                const unsigned bits = __float_as_uint(fmaxf(v, 0.f));
                unsigned int* p = &minb[b * NH + hidx];
                if (bits < *((volatile unsigned int*)p)) atomicMin(p, bits);
            }
        }
    }
}

__global__ __launch_bounds__(256) void finalize_kernel(
    const float* __restrict__ dist, float* __restrict__ out, int B)
{
    constexpr float COLL = 0.005f;
    constexpr float CONT = 0.01f;
    const int total = B * NH;
    const int tid = threadIdx.x;
    double sum_d = 0.0, pen_sum = 0.0, att_sum = 0.0;
    int pen_cnt = 0, att_cnt = 0;
    for (int i = tid; i < total; i += 256) {
        const float d = sqrtf(fmaxf(dist[i], 0.f));
        sum_d += (double)d;
        if (d < COLL) { const float t = COLL - d; pen_sum += (double)(t * t); pen_cnt++; }
        const int n = i % NH;
        const bool isc = (n == 745) | (n == 317) | (n == 444) | (n == 556) |
                         (n == 673) | (n == 95)  | (n == 182) | (n == 234) |
                         (n == 279) | (n == 320);
        if (isc & (d > COLL) & (d < CONT)) { att_sum += (double)(d * d); att_cnt++; }
    }
    __shared__ double sd[256], sp[256], sa[256];
    __shared__ int    cp[256], ca[256];
    sd[tid] = sum_d; sp[tid] = pen_sum; sa[tid] = att_sum;
    cp[tid] = pen_cnt; ca[tid] = att_cnt;
    __syncthreads();
    for (int off = 128; off > 0; off >>= 1) {
        if (tid < off) {
            sd[tid] += sd[tid + off]; sp[tid] += sp[tid + off];
            sa[tid] += sa[tid + off];
            cp[tid] += cp[tid + off]; ca[tid] += ca[tid + off];
        }
        __syncthreads();
    }
    if (tid == 0) {
        const double pen_loss = cp[0] > 0 ? sp[0] / (double)cp[0] : 0.0;
        const double att_loss = ca[0] > 0 ? sa[0] / (double)ca[0] : 0.0;
        out[0] = (float)(100.0 * pen_loss + 10.0 * att_loss);
        out[1] = (float)pen_loss;
        out[2] = (float)att_loss;
        out[3] = (float)(sd[0] / (double)total);
        out[4] = (float)ca[0];
        out[5] = (float)cp[0];
    }
}

extern "C" void kernel_launch(void* const* d_in, const int* in_sizes, int n_in,
                              void* d_out, int out_size, void* d_ws, size_t ws_size,
                              hipStream_t stream) {
    const float* hand = (const float*)d_in[0];  // [B, 778, 3] fp32
    const float* obj  = (const float*)d_in[1];  // [B, V, 3]   fp32
    // d_in[2]/d_in[3] (faces): unused by the loss

    const int B = in_sizes[0] / (NH * 3);
    const int V = in_sizes[1] / (B * 3);
    const int total = B * V;
    const int nq = B * NH;
    const int nblocks = (nq + 15) / 16;   // 4 waves/block, 4 queries/wave

    // ws layout: [header 256B: Accs][parts nblocks*64B][cnt][buckets][ovf]
    char* ws = (char*)d_ws;
    Accs* acc = (Accs*)ws;
    Part* parts = (Part*)(ws + 256);
    const size_t parts_bytes = ((size_t)nblocks * sizeof(Part) + 255) & ~(size_t)255;
    int* cnt = (int*)(ws + 256 + parts_bytes);
    const size_t cnt_bytes = (size_t)B * NCELL * sizeof(int);
    float4* buckets = (float4*)(ws + 256 + parts_bytes + cnt_bytes);
    const size_t bkt_bytes = (size_t)B * NCELL * CAP * sizeof(float4);
    float4* ovf = (float4*)(ws + 256 + parts_bytes + cnt_bytes + bkt_bytes);
    const size_t need = 256 + parts_bytes + cnt_bytes + bkt_bytes +
                        (size_t)total * sizeof(float4);

    if (ws_size >= need) {
        // zero header + parts (harmless) + cell counts in one node
        hipMemsetAsync(ws, 0, 256 + parts_bytes + cnt_bytes, stream);
        bin_kernel<<<(total + 255) / 256, 256, 0, stream>>>(
            obj, cnt, &acc->ocnt, buckets, ovf, total, V);
        query_finalize_kernel<<<nblocks, 256, 0, stream>>>(
            hand, cnt, buckets, ovf, acc, parts, (float*)d_out, B, nblocks);
    } else {
        // brute-force fallback (uint bit-pattern mins == float d2)
        hipMemsetAsync(d_ws, 0x7F, (size_t)B * NH * sizeof(unsigned int), stream);
        dim3 grid(FNBX, (V + FCHUNK - 1) / FCHUNK, B);
        nn_brute_kernel<<<grid, FBLK, 0, stream>>>(hand, obj,
                                                   (unsigned int*)d_ws, V);
        finalize_kernel<<<1, 256, 0, stream>>>((const float*)d_ws,
                                               (float*)d_out, B);
    }
}